// Round 14
// baseline (631.193 us; speedup 1.0000x reference)
//
#include <hip/hip_runtime.h>

#define Bsz 8192
#define Lctx 64
#define Ddim 512
#define DK 64
#define Ttag 128
#define RQT 2   // batch rows per wave in k_qtilde

using f32x4 = __attribute__((ext_vector_type(4))) float;
using bf16x8 = __attribute__((ext_vector_type(8))) short;

__device__ __forceinline__ float wave_sum(float v) {
#pragma unroll
    for (int m = 32; m > 0; m >>= 1) v += __shfl_xor(v, m, 64);
    return v;
}

__device__ __forceinline__ float wave_max(float v) {
#pragma unroll
    for (int m = 32; m > 0; m >>= 1) v = fmaxf(v, __shfl_xor(v, m, 64));
    return v;
}

__device__ __forceinline__ float dot4(float4 a, float4 b) {
    return a.x * b.x + a.y * b.y + a.z * b.z + a.w * b.w;
}

__device__ __forceinline__ unsigned f2bf(float f) {  // RNE, low 16 valid
    unsigned int u = __float_as_uint(f);
    u = u + 0x7fffu + ((u >> 16) & 1u);
    return u >> 16;
}
__device__ __forceinline__ unsigned pack2(float a, float b) {
    return f2bf(a) | (f2bf(b) << 16);
}
__device__ __forceinline__ float bf2f(unsigned short u) { return __uint_as_float((unsigned)u << 16); }

// ---------------------------------------------------------------------------
// fp32 -> bf16 weight convert, all three MLP weights in one launch.
// ---------------------------------------------------------------------------
__global__ __launch_bounds__(256) void k_f2bf3(
    const float* __restrict__ s1, unsigned short* __restrict__ d1,
    const float* __restrict__ s2, unsigned short* __restrict__ d2,
    const float* __restrict__ s3, unsigned short* __restrict__ d3)
{
    int i = blockIdx.x * 256 + threadIdx.x;
    const float* s;
    unsigned short* d;
    if (i < 196608)      { s = s1; d = d1; }
    else if (i < 229376) { i -= 196608; s = s2; d = d2; }
    else if (i < 237568) { i -= 229376; s = s3; d = d3; }
    else return;
    const float4 v = ((const float4*)s)[i];
    uint2 w;
    w.x = pack2(v.x, v.y);
    w.y = pack2(v.z, v.w);
    *(uint2*)&d[(size_t)i * 4] = w;
}

// ---------------------------------------------------------------------------
// q̃[b] = W_K^T (W_Q c[b]).  RQT=2 rows per wave, grid 1024.
// ---------------------------------------------------------------------------
__global__ __launch_bounds__(256) void k_qtilde(
    const float* __restrict__ C, const float* __restrict__ WQ,
    const float* __restrict__ WK, float* __restrict__ qt)
{
    const int lane = threadIdx.x & 63;
    const int gw = blockIdx.x * 4 + (threadIdx.x >> 6);
    const int b0 = gw * RQT;

    float4 c0[RQT], c1[RQT];
#pragma unroll
    for (int r = 0; r < RQT; ++r) {
        const float4* row = (const float4*)(C + (size_t)(b0 + r) * Ddim);
        c0[r] = row[lane];
        c1[r] = row[64 + lane];
    }
    float tv[RQT];
#pragma unroll
    for (int r = 0; r < RQT; ++r) tv[r] = 0.f;
    for (int k = 0; k < DK; ++k) {
        const float4* wrow = (const float4*)(WQ + (size_t)k * Ddim);
        const float4 w0 = wrow[lane];
        const float4 w1 = wrow[64 + lane];
#pragma unroll
        for (int r = 0; r < RQT; ++r) {
            float p = dot4(c0[r], w0) + dot4(c1[r], w1);
            p = wave_sum(p);
            if (lane == k) tv[r] = p;
        }
    }
    float4 a0[RQT], a1[RQT];
#pragma unroll
    for (int r = 0; r < RQT; ++r) {
        a0[r] = make_float4(0.f, 0.f, 0.f, 0.f);
        a1[r] = make_float4(0.f, 0.f, 0.f, 0.f);
    }
    for (int k = 0; k < DK; ++k) {
        const float4* wrow = (const float4*)(WK + (size_t)k * Ddim);
        const float4 w0 = wrow[lane];
        const float4 w1 = wrow[64 + lane];
#pragma unroll
        for (int r = 0; r < RQT; ++r) {
            const float tk = __shfl(tv[r], k, 64);
            a0[r].x += tk * w0.x; a0[r].y += tk * w0.y;
            a0[r].z += tk * w0.z; a0[r].w += tk * w0.w;
            a1[r].x += tk * w1.x; a1[r].y += tk * w1.y;
            a1[r].z += tk * w1.z; a1[r].w += tk * w1.w;
        }
    }
#pragma unroll
    for (int r = 0; r < RQT; ++r) {
        float4* orow = (float4*)(qt + (size_t)(b0 + r) * Ddim);
        orow[lane] = a0[r];
        orow[64 + lane] = a1[r];
    }
}

// ---------------------------------------------------------------------------
// Fused ragged attention + wide — R13's lean flash-partial kernel, verbatim.
// NOTE: this round the host launches this kernel TWICE (idempotent) as a
// duration probe: total_time - 406.8us baseline = this kernel's duration.
// ---------------------------------------------------------------------------
__global__ __launch_bounds__(256, 8) void k_attn_wide(
    const float* __restrict__ X, const float* __restrict__ qt,
    const int* __restrict__ clen, const float* __restrict__ mdesc,
    const float* __restrict__ cand,
    const float* __restrict__ mt, const float* __restrict__ tt,
    const float* __restrict__ cp, const float* __restrict__ ww,
    const float* __restrict__ wb,
    unsigned short* __restrict__ din, float* __restrict__ wl)
{
    __shared__ float sl[Lctx];
    __shared__ float part[4][Ddim];   // 8 KB per-wave flash partials
    __shared__ float Mw[4];
    __shared__ float red[4];
    __shared__ float MD[2];           // global max, 1/denom

    const int b = blockIdx.x;
    const int tid = threadIdx.x;
    const int wave = tid >> 6, lane = tid & 63;
    const int len = clen[b];
    const int nrw = (len > wave) ? ((len - wave + 3) >> 2) : 0;  // strided by 4

    const float4* xb = (const float4*)(X + (size_t)b * Lctx * Ddim);

    float4 y0 = make_float4(0.f, 0.f, 0.f, 0.f);
    float4 y1 = make_float4(0.f, 0.f, 0.f, 0.f);
    float mw = -1e30f;

    if (nrw > 0) {
        const float4* qrow = (const float4*)(qt + (size_t)b * Ddim);
        const float4 q0 = qrow[lane];
        const float4 q1 = qrow[64 + lane];
        for (int k = 0; k < nrw; k += 2) {
            const int l0 = wave + k * 4;
            const int l1 = wave + min(k + 1, nrw - 1) * 4;  // clamp: dup row
            const float4 a0 = xb[l0 * 128 + lane];
            const float4 a1 = xb[l0 * 128 + 64 + lane];
            const float4 c0 = xb[l1 * 128 + lane];
            const float4 c1 = xb[l1 * 128 + 64 + lane];
            float s0 = dot4(a0, q0) + dot4(a1, q1);
            float s1 = dot4(c0, q0) + dot4(c1, q1);
            s0 = wave_sum(s0);
            s1 = wave_sum(s1);
            const bool has1 = (k + 1 < nrw);
            if (lane == 0) {
                sl[l0] = s0;
                if (has1) sl[l1] = s1;
            }
            const float pm = has1 ? fmaxf(s0, s1) : s0;
            const float mn = fmaxf(mw, pm);
            const float scale = __expf(mw - mn);   // first chunk: exp(-huge)=0
            const float e0 = __expf(s0 - mn);
            const float e1 = has1 ? __expf(s1 - mn) : 0.f;
            y0.x = y0.x * scale + e0 * a0.x + e1 * c0.x;
            y0.y = y0.y * scale + e0 * a0.y + e1 * c0.y;
            y0.z = y0.z * scale + e0 * a0.z + e1 * c0.z;
            y0.w = y0.w * scale + e0 * a0.w + e1 * c0.w;
            y1.x = y1.x * scale + e0 * a1.x + e1 * c1.x;
            y1.y = y1.y * scale + e0 * a1.y + e1 * c1.y;
            y1.z = y1.z * scale + e0 * a1.z + e1 * c1.z;
            y1.w = y1.w * scale + e0 * a1.w + e1 * c1.w;
            mw = mn;
        }
    }
    *(float4*)&part[wave][lane * 4] = y0;
    *(float4*)&part[wave][256 + lane * 4] = y1;
    if (lane == 0) Mw[wave] = mw;

    // ---- wide branch stream ----
    float wacc = 0.f;
    if (tid < 64) {
        float4 v;
        if (tid < 32) v = ((const float4*)(mt + (size_t)b * Ttag))[tid];
        else          v = ((const float4*)(tt + (size_t)b * Ttag))[tid - 32];
        wacc += dot4(v, ((const float4*)ww)[tid]);
    }
    {
        const float4* cp4 = (const float4*)(cp + (size_t)b * (Ttag * Ttag));
        const float4* ww4 = (const float4*)(ww + 2 * Ttag);
#pragma unroll 2
        for (int i = tid; i < (Ttag * Ttag) / 4; i += 256)
            wacc += dot4(cp4[i], ww4[i]);
    }
    wacc = wave_sum(wacc);
    if (lane == 0) red[wave] = wacc;

    const float4 mv = (tid < 128)
        ? ((const float4*)(mdesc + (size_t)b * Ddim))[tid]
        : ((const float4*)(cand + (size_t)b * Ddim))[tid - 128];

    __syncthreads();

    if (wave == 0) {
        const float s = (lane < len) ? sl[lane] : -1e30f;
        const float m = wave_max(s);
        const float e = (lane < len) ? __expf(s - m) : 0.f;
        const float d = wave_sum(e);
        if (lane == 0) {
            MD[0] = m;
            MD[1] = 1.f / fmaxf(d, 1e-30f);
        }
    }
    __syncthreads();

    const float Mg = MD[0], rD = MD[1];
    const float f0 = __expf(Mw[0] - Mg) * rD;
    const float f1 = __expf(Mw[1] - Mg) * rD;
    const float f2 = __expf(Mw[2] - Mg) * rD;
    const float f3 = __expf(Mw[3] - Mg) * rD;

    unsigned short* dr = din + (size_t)b * 1536;
    {
        const int d0 = tid * 2;
        const float2 p0 = *(const float2*)&part[0][d0];
        const float2 p1 = *(const float2*)&part[1][d0];
        const float2 p2 = *(const float2*)&part[2][d0];
        const float2 p3 = *(const float2*)&part[3][d0];
        const float vx = p0.x * f0 + p1.x * f1 + p2.x * f2 + p3.x * f3;
        const float vy = p0.y * f0 + p1.y * f1 + p2.y * f2 + p3.y * f3;
        *(unsigned*)&dr[512 + d0] = pack2(vx, vy);
    }
    {
        uint2 w;
        w.x = pack2(mv.x, mv.y);
        w.y = pack2(mv.z, mv.w);
        const int off = (tid < 128) ? tid * 4 : 1024 + (tid - 128) * 4;
        *(uint2*)&dr[off] = w;
    }
    if (tid == 0) wl[b] = red[0] + red[1] + red[2] + red[3] + wb[0];
}

// ---------------------------------------------------------------------------
// bf16 MFMA GEMM: C[M,N] = act(A[M,K] @ W[N,K]^T + bias).  BM=BN=128.
// ---------------------------------------------------------------------------
__global__ __launch_bounds__(256) void k_gemm_bf16(
    const unsigned short* __restrict__ A, const unsigned short* __restrict__ W,
    const float* __restrict__ bias, unsigned short* __restrict__ C,
    const int K, const int N, const int relu)
{
    __shared__ unsigned short As[128][72];
    __shared__ unsigned short Bs[128][72];
    const int tid = threadIdx.x;
    const int wave = tid >> 6, lane = tid & 63;
    const int wm = wave >> 1, wn = wave & 1;
    const size_t m0 = (size_t)blockIdx.x * 128;
    const size_t n0 = (size_t)blockIdx.y * 128;

    f32x4 acc[4][4];
#pragma unroll
    for (int i = 0; i < 4; ++i)
#pragma unroll
        for (int j = 0; j < 4; ++j) acc[i][j] = (f32x4){0.f, 0.f, 0.f, 0.f};

    uint4 pa[4], pb[4];
    auto loadA = [&](int k0) {
#pragma unroll
        for (int j = 0; j < 4; ++j) {
            const int i = tid + j * 256;
            const int row = i >> 3, c8 = (i & 7) * 8;
            pa[j] = *(const uint4*)(A + (m0 + row) * (size_t)K + k0 + c8);
        }
    };
    auto loadB = [&](int k0) {
#pragma unroll
        for (int j = 0; j < 4; ++j) {
            const int i = tid + j * 256;
            const int row = i >> 3, c8 = (i & 7) * 8;
            pb[j] = *(const uint4*)(W + (n0 + row) * (size_t)K + k0 + c8);
        }
    };

    loadA(0);
    loadB(0);
    for (int k0 = 0; k0 < K; k0 += 64) {
        __syncthreads();
#pragma unroll
        for (int j = 0; j < 4; ++j) {
            const int i = tid + j * 256;
            const int row = i >> 3, c8 = (i & 7) * 8;
            *(uint4*)&As[row][c8] = pa[j];
            *(uint4*)&Bs[row][c8] = pb[j];
        }
        __syncthreads();
        if (k0 + 64 < K) { loadA(k0 + 64); loadB(k0 + 64); }
#pragma unroll
        for (int kk = 0; kk < 2; ++kk) {
            const int krow = kk * 32 + (lane >> 4) * 8;
            bf16x8 af[4], bfr[4];
#pragma unroll
            for (int mm = 0; mm < 4; ++mm)
                af[mm] = *(const bf16x8*)&As[wm * 64 + mm * 16 + (lane & 15)][krow];
#pragma unroll
            for (int nn = 0; nn < 4; ++nn)
                bfr[nn] = *(const bf16x8*)&Bs[wn * 64 + nn * 16 + (lane & 15)][krow];
#pragma unroll
            for (int mm = 0; mm < 4; ++mm)
#pragma unroll
                for (int nn = 0; nn < 4; ++nn)
                    acc[mm][nn] = __builtin_amdgcn_mfma_f32_16x16x32_bf16(
                        af[mm], bfr[nn], acc[mm][nn], 0, 0, 0);
        }
    }

#pragma unroll
    for (int nn = 0; nn < 4; ++nn) {
        const int col = (int)n0 + wn * 64 + nn * 16 + (lane & 15);
        const float bv = bias[col];
#pragma unroll
        for (int mm = 0; mm < 4; ++mm) {
#pragma unroll
            for (int r = 0; r < 4; ++r) {
                const size_t row = m0 + wm * 64 + mm * 16 + (lane >> 4) * 4 + r;
                float v = acc[mm][nn][r] + bv;
                if (relu) v = fmaxf(v, 0.f);
                C[row * N + col] = (unsigned short)f2bf(v);
            }
        }
    }
}

// ---------------------------------------------------------------------------
// Final: deep_out = h3 . d4w + d4b; out = sigmoid(ww*sigmoid(wide)+dw*deep+bias)
// ---------------------------------------------------------------------------
__global__ __launch_bounds__(256) void k_final(
    const unsigned short* __restrict__ h3, const float* __restrict__ d4w,
    const float* __restrict__ d4b, const float* __restrict__ wl,
    const float* __restrict__ wwt, const float* __restrict__ dwt,
    const float* __restrict__ bs, float* __restrict__ out)
{
    const int lane = threadIdx.x & 63;
    const int b = blockIdx.x * 4 + (threadIdx.x >> 6);
    const unsigned short* hr = h3 + (size_t)b * 128;
    float v = bf2f(hr[lane]) * d4w[lane] + bf2f(hr[64 + lane]) * d4w[64 + lane];
    v = wave_sum(v);
    if (lane == 0) {
        const float deep = v + d4b[0];
        const float wo = 1.f / (1.f + __expf(-wl[b]));
        const float z = wwt[0] * wo + dwt[0] * deep + bs[0];
        out[b] = 1.f / (1.f + __expf(-z));
    }
}

extern "C" void kernel_launch(void* const* d_in, const int* in_sizes, int n_in,
                              void* d_out, int out_size, void* d_ws, size_t ws_size,
                              hipStream_t stream)
{
    const float* mt    = (const float*)d_in[0];
    const float* tt    = (const float*)d_in[1];
    const float* cp    = (const float*)d_in[2];
    const float* X     = (const float*)d_in[3];
    const float* cand  = (const float*)d_in[4];
    const float* mdesc = (const float*)d_in[5];
    const int*   clen  = (const int*)d_in[6];
    const float* WK    = (const float*)d_in[7];
    const float* WQ    = (const float*)d_in[8];
    const float* ww    = (const float*)d_in[9];
    const float* wb    = (const float*)d_in[10];
    const float* d1w   = (const float*)d_in[11];
    const float* d1b   = (const float*)d_in[12];
    const float* d2w   = (const float*)d_in[13];
    const float* d2b   = (const float*)d_in[14];
    const float* d3w   = (const float*)d_in[15];
    const float* d3b   = (const float*)d_in[16];
    const float* d4w   = (const float*)d_in[17];
    const float* d4b   = (const float*)d_in[18];
    const float* wwt   = (const float*)d_in[19];
    const float* dwt   = (const float*)d_in[20];
    const float* bs    = (const float*)d_in[21];
    float* out = (float*)d_out;

    // workspace layout (bytes)
    char* w = (char*)d_ws;
    unsigned short* din = (unsigned short*)w;            w += (size_t)Bsz * 1536 * 2;
    float* qt           = (float*)w;                     w += (size_t)Bsz * 512 * 4;
    unsigned short* h1  = (unsigned short*)w;            w += (size_t)Bsz * 512 * 2;
    unsigned short* h2  = (unsigned short*)w;            w += (size_t)Bsz * 256 * 2;
    unsigned short* h3  = (unsigned short*)w;            w += (size_t)Bsz * 128 * 2;
    float* wl           = (float*)w;                     w += (size_t)Bsz * 4;
    unsigned short* w1b = (unsigned short*)w;            w += (size_t)512 * 1536 * 2;
    unsigned short* w2b = (unsigned short*)w;            w += (size_t)256 * 512 * 2;
    unsigned short* w3b = (unsigned short*)w;            w += (size_t)128 * 256 * 2;

    hipLaunchKernelGGL(k_f2bf3, dim3(928), dim3(256), 0, stream,
                       d1w, w1b, d2w, w2b, d3w, w3b);
    hipLaunchKernelGGL(k_qtilde, dim3(Bsz / (RQT * 4)), dim3(256), 0, stream,
                       cand, WQ, WK, qt);
    // --- duration probe: launch the (idempotent) attn kernel TWICE.
    // total_dur - 406.8us (R13 baseline, identical otherwise) = T_attn.
    hipLaunchKernelGGL(k_attn_wide, dim3(Bsz), dim3(256), 0, stream,
                       X, qt, clen, mdesc, cand, mt, tt, cp, ww, wb, din, wl);
    hipLaunchKernelGGL(k_attn_wide, dim3(Bsz), dim3(256), 0, stream,
                       X, qt, clen, mdesc, cand, mt, tt, cp, ww, wb, din, wl);
    hipLaunchKernelGGL(k_gemm_bf16, dim3(64, 4), dim3(256), 0, stream,
                       din, w1b, d1b, h1, 1536, 512, 1);
    hipLaunchKernelGGL(k_gemm_bf16, dim3(64, 2), dim3(256), 0, stream,
                       h1, w2b, d2b, h2, 512, 256, 1);
    hipLaunchKernelGGL(k_gemm_bf16, dim3(64, 1), dim3(256), 0, stream,
                       h2, w3b, d3b, h3, 256, 128, 1);
    hipLaunchKernelGGL(k_final, dim3(Bsz / 4), dim3(256), 0, stream,
                       h3, d4w, d4b, wl, wwt, dwt, bs, out);
}

// Round 15
// 508.513 us; speedup vs baseline: 1.2413x; 1.2413x over previous
//
#include <hip/hip_runtime.h>

#define Bsz 8192
#define Lctx 64
#define Ddim 512
#define DK 64
#define Ttag 128
#define RQT 2   // batch rows per wave in k_qtilde

using f32x4 = __attribute__((ext_vector_type(4))) float;
using bf16x8 = __attribute__((ext_vector_type(8))) short;

__device__ __forceinline__ float wave_sum(float v) {
#pragma unroll
    for (int m = 32; m > 0; m >>= 1) v += __shfl_xor(v, m, 64);
    return v;
}

__device__ __forceinline__ float wave_max(float v) {
#pragma unroll
    for (int m = 32; m > 0; m >>= 1) v = fmaxf(v, __shfl_xor(v, m, 64));
    return v;
}

__device__ __forceinline__ float dot4(float4 a, float4 b) {
    return a.x * b.x + a.y * b.y + a.z * b.z + a.w * b.w;
}

__device__ __forceinline__ unsigned f2bf(float f) {  // RNE, low 16 valid
    unsigned int u = __float_as_uint(f);
    u = u + 0x7fffu + ((u >> 16) & 1u);
    return u >> 16;
}
__device__ __forceinline__ unsigned pack2(float a, float b) {
    return f2bf(a) | (f2bf(b) << 16);
}
__device__ __forceinline__ float bf2f(unsigned short u) { return __uint_as_float((unsigned)u << 16); }

// ---------------------------------------------------------------------------
// fp32 -> bf16 weight convert, all three MLP weights in one launch.
// ---------------------------------------------------------------------------
__global__ __launch_bounds__(256) void k_f2bf3(
    const float* __restrict__ s1, unsigned short* __restrict__ d1,
    const float* __restrict__ s2, unsigned short* __restrict__ d2,
    const float* __restrict__ s3, unsigned short* __restrict__ d3)
{
    int i = blockIdx.x * 256 + threadIdx.x;
    const float* s;
    unsigned short* d;
    if (i < 196608)      { s = s1; d = d1; }
    else if (i < 229376) { i -= 196608; s = s2; d = d2; }
    else if (i < 237568) { i -= 229376; s = s3; d = d3; }
    else return;
    const float4 v = ((const float4*)s)[i];
    uint2 w;
    w.x = pack2(v.x, v.y);
    w.y = pack2(v.z, v.w);
    *(uint2*)&d[(size_t)i * 4] = w;
}

// ---------------------------------------------------------------------------
// q̃[b] = W_K^T (W_Q c[b]).  RQT=2 rows per wave, grid 1024.
// ---------------------------------------------------------------------------
__global__ __launch_bounds__(256) void k_qtilde(
    const float* __restrict__ C, const float* __restrict__ WQ,
    const float* __restrict__ WK, float* __restrict__ qt)
{
    const int lane = threadIdx.x & 63;
    const int gw = blockIdx.x * 4 + (threadIdx.x >> 6);
    const int b0 = gw * RQT;

    float4 c0[RQT], c1[RQT];
#pragma unroll
    for (int r = 0; r < RQT; ++r) {
        const float4* row = (const float4*)(C + (size_t)(b0 + r) * Ddim);
        c0[r] = row[lane];
        c1[r] = row[64 + lane];
    }
    float tv[RQT];
#pragma unroll
    for (int r = 0; r < RQT; ++r) tv[r] = 0.f;
    for (int k = 0; k < DK; ++k) {
        const float4* wrow = (const float4*)(WQ + (size_t)k * Ddim);
        const float4 w0 = wrow[lane];
        const float4 w1 = wrow[64 + lane];
#pragma unroll
        for (int r = 0; r < RQT; ++r) {
            float p = dot4(c0[r], w0) + dot4(c1[r], w1);
            p = wave_sum(p);
            if (lane == k) tv[r] = p;
        }
    }
    float4 a0[RQT], a1[RQT];
#pragma unroll
    for (int r = 0; r < RQT; ++r) {
        a0[r] = make_float4(0.f, 0.f, 0.f, 0.f);
        a1[r] = make_float4(0.f, 0.f, 0.f, 0.f);
    }
    for (int k = 0; k < DK; ++k) {
        const float4* wrow = (const float4*)(WK + (size_t)k * Ddim);
        const float4 w0 = wrow[lane];
        const float4 w1 = wrow[64 + lane];
#pragma unroll
        for (int r = 0; r < RQT; ++r) {
            const float tk = __shfl(tv[r], k, 64);
            a0[r].x += tk * w0.x; a0[r].y += tk * w0.y;
            a0[r].z += tk * w0.z; a0[r].w += tk * w0.w;
            a1[r].x += tk * w1.x; a1[r].y += tk * w1.y;
            a1[r].z += tk * w1.z; a1[r].w += tk * w1.w;
        }
    }
#pragma unroll
    for (int r = 0; r < RQT; ++r) {
        float4* orow = (float4*)(qt + (size_t)(b0 + r) * Ddim);
        orow[lane] = a0[r];
        orow[64 + lane] = a1[r];
    }
}

// ---------------------------------------------------------------------------
// Fused ragged attention + wide — R13's lean flash-partial kernel, verbatim.
// (Single launch again this round; measured T_attn = 224 us in R14.)
// ---------------------------------------------------------------------------
__global__ __launch_bounds__(256, 8) void k_attn_wide(
    const float* __restrict__ X, const float* __restrict__ qt,
    const int* __restrict__ clen, const float* __restrict__ mdesc,
    const float* __restrict__ cand,
    const float* __restrict__ mt, const float* __restrict__ tt,
    const float* __restrict__ cp, const float* __restrict__ ww,
    const float* __restrict__ wb,
    unsigned short* __restrict__ din, float* __restrict__ wl)
{
    __shared__ float sl[Lctx];
    __shared__ float part[4][Ddim];   // 8 KB per-wave flash partials
    __shared__ float Mw[4];
    __shared__ float red[4];
    __shared__ float MD[2];           // global max, 1/denom

    const int b = blockIdx.x;
    const int tid = threadIdx.x;
    const int wave = tid >> 6, lane = tid & 63;
    const int len = clen[b];
    const int nrw = (len > wave) ? ((len - wave + 3) >> 2) : 0;  // strided by 4

    const float4* xb = (const float4*)(X + (size_t)b * Lctx * Ddim);

    float4 y0 = make_float4(0.f, 0.f, 0.f, 0.f);
    float4 y1 = make_float4(0.f, 0.f, 0.f, 0.f);
    float mw = -1e30f;

    if (nrw > 0) {
        const float4* qrow = (const float4*)(qt + (size_t)b * Ddim);
        const float4 q0 = qrow[lane];
        const float4 q1 = qrow[64 + lane];
        for (int k = 0; k < nrw; k += 2) {
            const int l0 = wave + k * 4;
            const int l1 = wave + min(k + 1, nrw - 1) * 4;  // clamp: dup row
            const float4 a0 = xb[l0 * 128 + lane];
            const float4 a1 = xb[l0 * 128 + 64 + lane];
            const float4 c0 = xb[l1 * 128 + lane];
            const float4 c1 = xb[l1 * 128 + 64 + lane];
            float s0 = dot4(a0, q0) + dot4(a1, q1);
            float s1 = dot4(c0, q0) + dot4(c1, q1);
            s0 = wave_sum(s0);
            s1 = wave_sum(s1);
            const bool has1 = (k + 1 < nrw);
            if (lane == 0) {
                sl[l0] = s0;
                if (has1) sl[l1] = s1;
            }
            const float pm = has1 ? fmaxf(s0, s1) : s0;
            const float mn = fmaxf(mw, pm);
            const float scale = __expf(mw - mn);   // first chunk: exp(-huge)=0
            const float e0 = __expf(s0 - mn);
            const float e1 = has1 ? __expf(s1 - mn) : 0.f;
            y0.x = y0.x * scale + e0 * a0.x + e1 * c0.x;
            y0.y = y0.y * scale + e0 * a0.y + e1 * c0.y;
            y0.z = y0.z * scale + e0 * a0.z + e1 * c0.z;
            y0.w = y0.w * scale + e0 * a0.w + e1 * c0.w;
            y1.x = y1.x * scale + e0 * a1.x + e1 * c1.x;
            y1.y = y1.y * scale + e0 * a1.y + e1 * c1.y;
            y1.z = y1.z * scale + e0 * a1.z + e1 * c1.z;
            y1.w = y1.w * scale + e0 * a1.w + e1 * c1.w;
            mw = mn;
        }
    }
    *(float4*)&part[wave][lane * 4] = y0;
    *(float4*)&part[wave][256 + lane * 4] = y1;
    if (lane == 0) Mw[wave] = mw;

    // ---- wide branch stream ----
    float wacc = 0.f;
    if (tid < 64) {
        float4 v;
        if (tid < 32) v = ((const float4*)(mt + (size_t)b * Ttag))[tid];
        else          v = ((const float4*)(tt + (size_t)b * Ttag))[tid - 32];
        wacc += dot4(v, ((const float4*)ww)[tid]);
    }
    {
        const float4* cp4 = (const float4*)(cp + (size_t)b * (Ttag * Ttag));
        const float4* ww4 = (const float4*)(ww + 2 * Ttag);
#pragma unroll 2
        for (int i = tid; i < (Ttag * Ttag) / 4; i += 256)
            wacc += dot4(cp4[i], ww4[i]);
    }
    wacc = wave_sum(wacc);
    if (lane == 0) red[wave] = wacc;

    const float4 mv = (tid < 128)
        ? ((const float4*)(mdesc + (size_t)b * Ddim))[tid]
        : ((const float4*)(cand + (size_t)b * Ddim))[tid - 128];

    __syncthreads();

    if (wave == 0) {
        const float s = (lane < len) ? sl[lane] : -1e30f;
        const float m = wave_max(s);
        const float e = (lane < len) ? __expf(s - m) : 0.f;
        const float d = wave_sum(e);
        if (lane == 0) {
            MD[0] = m;
            MD[1] = 1.f / fmaxf(d, 1e-30f);
        }
    }
    __syncthreads();

    const float Mg = MD[0], rD = MD[1];
    const float f0 = __expf(Mw[0] - Mg) * rD;
    const float f1 = __expf(Mw[1] - Mg) * rD;
    const float f2 = __expf(Mw[2] - Mg) * rD;
    const float f3 = __expf(Mw[3] - Mg) * rD;

    unsigned short* dr = din + (size_t)b * 1536;
    {
        const int d0 = tid * 2;
        const float2 p0 = *(const float2*)&part[0][d0];
        const float2 p1 = *(const float2*)&part[1][d0];
        const float2 p2 = *(const float2*)&part[2][d0];
        const float2 p3 = *(const float2*)&part[3][d0];
        const float vx = p0.x * f0 + p1.x * f1 + p2.x * f2 + p3.x * f3;
        const float vy = p0.y * f0 + p1.y * f1 + p2.y * f2 + p3.y * f3;
        *(unsigned*)&dr[512 + d0] = pack2(vx, vy);
    }
    {
        uint2 w;
        w.x = pack2(mv.x, mv.y);
        w.y = pack2(mv.z, mv.w);
        const int off = (tid < 128) ? tid * 4 : 1024 + (tid - 128) * 4;
        *(uint2*)&dr[off] = w;
    }
    if (tid == 0) wl[b] = red[0] + red[1] + red[2] + red[3] + wb[0];
}

// ---------------------------------------------------------------------------
// bf16 MFMA GEMM: C[M,N] = act(A[M,K] @ W[N,K]^T + bias).  BM=BN=128.
// ---------------------------------------------------------------------------
__global__ __launch_bounds__(256) void k_gemm_bf16(
    const unsigned short* __restrict__ A, const unsigned short* __restrict__ W,
    const float* __restrict__ bias, unsigned short* __restrict__ C,
    const int K, const int N, const int relu)
{
    __shared__ unsigned short As[128][72];
    __shared__ unsigned short Bs[128][72];
    const int tid = threadIdx.x;
    const int wave = tid >> 6, lane = tid & 63;
    const int wm = wave >> 1, wn = wave & 1;
    const size_t m0 = (size_t)blockIdx.x * 128;
    const size_t n0 = (size_t)blockIdx.y * 128;

    f32x4 acc[4][4];
#pragma unroll
    for (int i = 0; i < 4; ++i)
#pragma unroll
        for (int j = 0; j < 4; ++j) acc[i][j] = (f32x4){0.f, 0.f, 0.f, 0.f};

    uint4 pa[4], pb[4];
    auto loadA = [&](int k0) {
#pragma unroll
        for (int j = 0; j < 4; ++j) {
            const int i = tid + j * 256;
            const int row = i >> 3, c8 = (i & 7) * 8;
            pa[j] = *(const uint4*)(A + (m0 + row) * (size_t)K + k0 + c8);
        }
    };
    auto loadB = [&](int k0) {
#pragma unroll
        for (int j = 0; j < 4; ++j) {
            const int i = tid + j * 256;
            const int row = i >> 3, c8 = (i & 7) * 8;
            pb[j] = *(const uint4*)(W + (n0 + row) * (size_t)K + k0 + c8);
        }
    };

    loadA(0);
    loadB(0);
    for (int k0 = 0; k0 < K; k0 += 64) {
        __syncthreads();
#pragma unroll
        for (int j = 0; j < 4; ++j) {
            const int i = tid + j * 256;
            const int row = i >> 3, c8 = (i & 7) * 8;
            *(uint4*)&As[row][c8] = pa[j];
            *(uint4*)&Bs[row][c8] = pb[j];
        }
        __syncthreads();
        if (k0 + 64 < K) { loadA(k0 + 64); loadB(k0 + 64); }
#pragma unroll
        for (int kk = 0; kk < 2; ++kk) {
            const int krow = kk * 32 + (lane >> 4) * 8;
            bf16x8 af[4], bfr[4];
#pragma unroll
            for (int mm = 0; mm < 4; ++mm)
                af[mm] = *(const bf16x8*)&As[wm * 64 + mm * 16 + (lane & 15)][krow];
#pragma unroll
            for (int nn = 0; nn < 4; ++nn)
                bfr[nn] = *(const bf16x8*)&Bs[wn * 64 + nn * 16 + (lane & 15)][krow];
#pragma unroll
            for (int mm = 0; mm < 4; ++mm)
#pragma unroll
                for (int nn = 0; nn < 4; ++nn)
                    acc[mm][nn] = __builtin_amdgcn_mfma_f32_16x16x32_bf16(
                        af[mm], bfr[nn], acc[mm][nn], 0, 0, 0);
        }
    }

#pragma unroll
    for (int nn = 0; nn < 4; ++nn) {
        const int col = (int)n0 + wn * 64 + nn * 16 + (lane & 15);
        const float bv = bias[col];
#pragma unroll
        for (int mm = 0; mm < 4; ++mm) {
#pragma unroll
            for (int r = 0; r < 4; ++r) {
                const size_t row = m0 + wm * 64 + mm * 16 + (lane >> 4) * 4 + r;
                float v = acc[mm][nn][r] + bv;
                if (relu) v = fmaxf(v, 0.f);
                C[row * N + col] = (unsigned short)f2bf(v);
            }
        }
    }
}

// ---------------------------------------------------------------------------
// Final: deep_out = h3 . d4w + d4b; out = sigmoid(ww*sigmoid(wide)+dw*deep+bias)
// ---------------------------------------------------------------------------
__global__ __launch_bounds__(256) void k_final(
    const unsigned short* __restrict__ h3, const float* __restrict__ d4w,
    const float* __restrict__ d4b, const float* __restrict__ wl,
    const float* __restrict__ wwt, const float* __restrict__ dwt,
    const float* __restrict__ bs, float* __restrict__ out)
{
    const int lane = threadIdx.x & 63;
    const int b = blockIdx.x * 4 + (threadIdx.x >> 6);
    const unsigned short* hr = h3 + (size_t)b * 128;
    float v = bf2f(hr[lane]) * d4w[lane] + bf2f(hr[64 + lane]) * d4w[64 + lane];
    v = wave_sum(v);
    if (lane == 0) {
        const float deep = v + d4b[0];
        const float wo = 1.f / (1.f + __expf(-wl[b]));
        const float z = wwt[0] * wo + dwt[0] * deep + bs[0];
        out[b] = 1.f / (1.f + __expf(-z));
    }
}

extern "C" void kernel_launch(void* const* d_in, const int* in_sizes, int n_in,
                              void* d_out, int out_size, void* d_ws, size_t ws_size,
                              hipStream_t stream)
{
    const float* mt    = (const float*)d_in[0];
    const float* tt    = (const float*)d_in[1];
    const float* cp    = (const float*)d_in[2];
    const float* X     = (const float*)d_in[3];
    const float* cand  = (const float*)d_in[4];
    const float* mdesc = (const float*)d_in[5];
    const int*   clen  = (const int*)d_in[6];
    const float* WK    = (const float*)d_in[7];
    const float* WQ    = (const float*)d_in[8];
    const float* ww    = (const float*)d_in[9];
    const float* wb    = (const float*)d_in[10];
    const float* d1w   = (const float*)d_in[11];
    const float* d1b   = (const float*)d_in[12];
    const float* d2w   = (const float*)d_in[13];
    const float* d2b   = (const float*)d_in[14];
    const float* d3w   = (const float*)d_in[15];
    const float* d3b   = (const float*)d_in[16];
    const float* d4w   = (const float*)d_in[17];
    const float* d4b   = (const float*)d_in[18];
    const float* wwt   = (const float*)d_in[19];
    const float* dwt   = (const float*)d_in[20];
    const float* bs    = (const float*)d_in[21];
    float* out = (float*)d_out;

    // workspace layout (bytes)
    char* w = (char*)d_ws;
    unsigned short* din = (unsigned short*)w;            w += (size_t)Bsz * 1536 * 2;
    float* qt           = (float*)w;                     w += (size_t)Bsz * 512 * 4;
    unsigned short* h1  = (unsigned short*)w;            w += (size_t)Bsz * 512 * 2;
    unsigned short* h2  = (unsigned short*)w;            w += (size_t)Bsz * 256 * 2;
    unsigned short* h3  = (unsigned short*)w;            w += (size_t)Bsz * 128 * 2;
    float* wl           = (float*)w;                     w += (size_t)Bsz * 4;
    unsigned short* w1b = (unsigned short*)w;            w += (size_t)512 * 1536 * 2;
    unsigned short* w2b = (unsigned short*)w;            w += (size_t)256 * 512 * 2;
    unsigned short* w3b = (unsigned short*)w;            w += (size_t)128 * 256 * 2;

    hipLaunchKernelGGL(k_f2bf3, dim3(928), dim3(256), 0, stream,
                       d1w, w1b, d2w, w2b, d3w, w3b);
    hipLaunchKernelGGL(k_qtilde, dim3(Bsz / (RQT * 4)), dim3(256), 0, stream,
                       cand, WQ, WK, qt);
    hipLaunchKernelGGL(k_attn_wide, dim3(Bsz), dim3(256), 0, stream,
                       X, qt, clen, mdesc, cand, mt, tt, cp, ww, wb, din, wl);
    // --- duration probe #2: launch the (idempotent) deep stack TWICE.
    // total_dur - 406.8us (R13 baseline, identical otherwise) =
    //   T(gemm1+gemm2+gemm3+final incl. launch gaps).
    hipLaunchKernelGGL(k_gemm_bf16, dim3(64, 4), dim3(256), 0, stream,
                       din, w1b, d1b, h1, 1536, 512, 1);
    hipLaunchKernelGGL(k_gemm_bf16, dim3(64, 2), dim3(256), 0, stream,
                       h1, w2b, d2b, h2, 512, 256, 1);
    hipLaunchKernelGGL(k_gemm_bf16, dim3(64, 1), dim3(256), 0, stream,
                       h2, w3b, d3b, h3, 256, 128, 1);
    hipLaunchKernelGGL(k_final, dim3(Bsz / 4), dim3(256), 0, stream,
                       h3, d4w, d4b, wl, wwt, dwt, bs, out);
    hipLaunchKernelGGL(k_gemm_bf16, dim3(64, 4), dim3(256), 0, stream,
                       din, w1b, d1b, h1, 1536, 512, 1);
    hipLaunchKernelGGL(k_gemm_bf16, dim3(64, 2), dim3(256), 0, stream,
                       h1, w2b, d2b, h2, 512, 256, 1);
    hipLaunchKernelGGL(k_gemm_bf16, dim3(64, 1), dim3(256), 0, stream,
                       h2, w3b, d3b, h3, 256, 128, 1);
    hipLaunchKernelGGL(k_final, dim3(Bsz / 4), dim3(256), 0, stream,
                       h3, d4w, d4b, wl, wwt, dwt, bs, out);
}

// Round 16
// 416.936 us; speedup vs baseline: 1.5139x; 1.2196x over previous
//
#include <hip/hip_runtime.h>

#define Bsz 8192
#define Lctx 64
#define Ddim 512
#define DK 64
#define Ttag 128
#define RQT 2   // batch rows per wave in qtilde part of k_prep

using f32x4 = __attribute__((ext_vector_type(4))) float;
using bf16x8 = __attribute__((ext_vector_type(8))) short;

__device__ __forceinline__ float wave_sum(float v) {
#pragma unroll
    for (int m = 32; m > 0; m >>= 1) v += __shfl_xor(v, m, 64);
    return v;
}

__device__ __forceinline__ float wave_max(float v) {
#pragma unroll
    for (int m = 32; m > 0; m >>= 1) v = fmaxf(v, __shfl_xor(v, m, 64));
    return v;
}

__device__ __forceinline__ float dot4(float4 a, float4 b) {
    return a.x * b.x + a.y * b.y + a.z * b.z + a.w * b.w;
}

__device__ __forceinline__ unsigned f2bf(float f) {  // RNE, low 16 valid
    unsigned int u = __float_as_uint(f);
    u = u + 0x7fffu + ((u >> 16) & 1u);
    return u >> 16;
}
__device__ __forceinline__ unsigned pack2(float a, float b) {
    return f2bf(a) | (f2bf(b) << 16);
}

// ---------------------------------------------------------------------------
// Prep: blocks [0,1024) compute q̃ (RQT=2 rows/wave); blocks [1024,1952)
// convert the three MLP weights fp32->bf16 (f2bf blocks fill idle CUs).
// ---------------------------------------------------------------------------
__global__ __launch_bounds__(256) void k_prep(
    const float* __restrict__ C, const float* __restrict__ WQ,
    const float* __restrict__ WK, float* __restrict__ qt,
    const float* __restrict__ s1, unsigned short* __restrict__ d1,
    const float* __restrict__ s2, unsigned short* __restrict__ d2,
    const float* __restrict__ s3, unsigned short* __restrict__ d3)
{
    if (blockIdx.x >= 1024) {
        int i = (blockIdx.x - 1024) * 256 + threadIdx.x;   // < 237568 by grid
        const float* s;
        unsigned short* d;
        if (i < 196608)      { s = s1; d = d1; }
        else if (i < 229376) { i -= 196608; s = s2; d = d2; }
        else                 { i -= 229376; s = s3; d = d3; }
        const float4 v = ((const float4*)s)[i];
        uint2 w;
        w.x = pack2(v.x, v.y);
        w.y = pack2(v.z, v.w);
        *(uint2*)&d[(size_t)i * 4] = w;
        return;
    }

    const int lane = threadIdx.x & 63;
    const int gw = blockIdx.x * 4 + (threadIdx.x >> 6);
    const int b0 = gw * RQT;

    float4 c0[RQT], c1[RQT];
#pragma unroll
    for (int r = 0; r < RQT; ++r) {
        const float4* row = (const float4*)(C + (size_t)(b0 + r) * Ddim);
        c0[r] = row[lane];
        c1[r] = row[64 + lane];
    }
    float tv[RQT];
#pragma unroll
    for (int r = 0; r < RQT; ++r) tv[r] = 0.f;
    for (int k = 0; k < DK; ++k) {
        const float4* wrow = (const float4*)(WQ + (size_t)k * Ddim);
        const float4 w0 = wrow[lane];
        const float4 w1 = wrow[64 + lane];
#pragma unroll
        for (int r = 0; r < RQT; ++r) {
            float p = dot4(c0[r], w0) + dot4(c1[r], w1);
            p = wave_sum(p);
            if (lane == k) tv[r] = p;
        }
    }
    float4 a0[RQT], a1[RQT];
#pragma unroll
    for (int r = 0; r < RQT; ++r) {
        a0[r] = make_float4(0.f, 0.f, 0.f, 0.f);
        a1[r] = make_float4(0.f, 0.f, 0.f, 0.f);
    }
    for (int k = 0; k < DK; ++k) {
        const float4* wrow = (const float4*)(WK + (size_t)k * Ddim);
        const float4 w0 = wrow[lane];
        const float4 w1 = wrow[64 + lane];
#pragma unroll
        for (int r = 0; r < RQT; ++r) {
            const float tk = __shfl(tv[r], k, 64);
            a0[r].x += tk * w0.x; a0[r].y += tk * w0.y;
            a0[r].z += tk * w0.z; a0[r].w += tk * w0.w;
            a1[r].x += tk * w1.x; a1[r].y += tk * w1.y;
            a1[r].z += tk * w1.z; a1[r].w += tk * w1.w;
        }
    }
#pragma unroll
    for (int r = 0; r < RQT; ++r) {
        float4* orow = (float4*)(qt + (size_t)(b0 + r) * Ddim);
        orow[lane] = a0[r];
        orow[64 + lane] = a1[r];
    }
}

// ---------------------------------------------------------------------------
// Fused ragged attention + wide — R13's lean flash-partial kernel, verbatim
// (measured 224 us, ~80% of achievable HBM BW).
// ---------------------------------------------------------------------------
__global__ __launch_bounds__(256, 8) void k_attn_wide(
    const float* __restrict__ X, const float* __restrict__ qt,
    const int* __restrict__ clen, const float* __restrict__ mdesc,
    const float* __restrict__ cand,
    const float* __restrict__ mt, const float* __restrict__ tt,
    const float* __restrict__ cp, const float* __restrict__ ww,
    const float* __restrict__ wb,
    unsigned short* __restrict__ din, float* __restrict__ wl)
{
    __shared__ float sl[Lctx];
    __shared__ float part[4][Ddim];
    __shared__ float Mw[4];
    __shared__ float red[4];
    __shared__ float MD[2];

    const int b = blockIdx.x;
    const int tid = threadIdx.x;
    const int wave = tid >> 6, lane = tid & 63;
    const int len = clen[b];
    const int nrw = (len > wave) ? ((len - wave + 3) >> 2) : 0;

    const float4* xb = (const float4*)(X + (size_t)b * Lctx * Ddim);

    float4 y0 = make_float4(0.f, 0.f, 0.f, 0.f);
    float4 y1 = make_float4(0.f, 0.f, 0.f, 0.f);
    float mw = -1e30f;

    if (nrw > 0) {
        const float4* qrow = (const float4*)(qt + (size_t)b * Ddim);
        const float4 q0 = qrow[lane];
        const float4 q1 = qrow[64 + lane];
        for (int k = 0; k < nrw; k += 2) {
            const int l0 = wave + k * 4;
            const int l1 = wave + min(k + 1, nrw - 1) * 4;
            const float4 a0 = xb[l0 * 128 + lane];
            const float4 a1 = xb[l0 * 128 + 64 + lane];
            const float4 c0 = xb[l1 * 128 + lane];
            const float4 c1 = xb[l1 * 128 + 64 + lane];
            float s0 = dot4(a0, q0) + dot4(a1, q1);
            float s1 = dot4(c0, q0) + dot4(c1, q1);
            s0 = wave_sum(s0);
            s1 = wave_sum(s1);
            const bool has1 = (k + 1 < nrw);
            if (lane == 0) {
                sl[l0] = s0;
                if (has1) sl[l1] = s1;
            }
            const float pm = has1 ? fmaxf(s0, s1) : s0;
            const float mn = fmaxf(mw, pm);
            const float scale = __expf(mw - mn);
            const float e0 = __expf(s0 - mn);
            const float e1 = has1 ? __expf(s1 - mn) : 0.f;
            y0.x = y0.x * scale + e0 * a0.x + e1 * c0.x;
            y0.y = y0.y * scale + e0 * a0.y + e1 * c0.y;
            y0.z = y0.z * scale + e0 * a0.z + e1 * c0.z;
            y0.w = y0.w * scale + e0 * a0.w + e1 * c0.w;
            y1.x = y1.x * scale + e0 * a1.x + e1 * c1.x;
            y1.y = y1.y * scale + e0 * a1.y + e1 * c1.y;
            y1.z = y1.z * scale + e0 * a1.z + e1 * c1.z;
            y1.w = y1.w * scale + e0 * a1.w + e1 * c1.w;
            mw = mn;
        }
    }
    *(float4*)&part[wave][lane * 4] = y0;
    *(float4*)&part[wave][256 + lane * 4] = y1;
    if (lane == 0) Mw[wave] = mw;

    float wacc = 0.f;
    if (tid < 64) {
        float4 v;
        if (tid < 32) v = ((const float4*)(mt + (size_t)b * Ttag))[tid];
        else          v = ((const float4*)(tt + (size_t)b * Ttag))[tid - 32];
        wacc += dot4(v, ((const float4*)ww)[tid]);
    }
    {
        const float4* cp4 = (const float4*)(cp + (size_t)b * (Ttag * Ttag));
        const float4* ww4 = (const float4*)(ww + 2 * Ttag);
#pragma unroll 2
        for (int i = tid; i < (Ttag * Ttag) / 4; i += 256)
            wacc += dot4(cp4[i], ww4[i]);
    }
    wacc = wave_sum(wacc);
    if (lane == 0) red[wave] = wacc;

    const float4 mv = (tid < 128)
        ? ((const float4*)(mdesc + (size_t)b * Ddim))[tid]
        : ((const float4*)(cand + (size_t)b * Ddim))[tid - 128];

    __syncthreads();

    if (wave == 0) {
        const float s = (lane < len) ? sl[lane] : -1e30f;
        const float m = wave_max(s);
        const float e = (lane < len) ? __expf(s - m) : 0.f;
        const float d = wave_sum(e);
        if (lane == 0) {
            MD[0] = m;
            MD[1] = 1.f / fmaxf(d, 1e-30f);
        }
    }
    __syncthreads();

    const float Mg = MD[0], rD = MD[1];
    const float f0 = __expf(Mw[0] - Mg) * rD;
    const float f1 = __expf(Mw[1] - Mg) * rD;
    const float f2 = __expf(Mw[2] - Mg) * rD;
    const float f3 = __expf(Mw[3] - Mg) * rD;

    unsigned short* dr = din + (size_t)b * 1536;
    {
        const int d0 = tid * 2;
        const float2 p0 = *(const float2*)&part[0][d0];
        const float2 p1 = *(const float2*)&part[1][d0];
        const float2 p2 = *(const float2*)&part[2][d0];
        const float2 p3 = *(const float2*)&part[3][d0];
        const float vx = p0.x * f0 + p1.x * f1 + p2.x * f2 + p3.x * f3;
        const float vy = p0.y * f0 + p1.y * f1 + p2.y * f2 + p3.y * f3;
        *(unsigned*)&dr[512 + d0] = pack2(vx, vy);
    }
    {
        uint2 w;
        w.x = pack2(mv.x, mv.y);
        w.y = pack2(mv.z, mv.w);
        const int off = (tid < 128) ? tid * 4 : 1024 + (tid - 128) * 4;
        *(uint2*)&dr[off] = w;
    }
    if (tid == 0) wl[b] = red[0] + red[1] + red[2] + red[3] + wb[0];
}

// ---------------------------------------------------------------------------
// bf16 MFMA GEMM templated on BM/BN.  4 waves in 2x2, per-wave (BM/2)x(BN/2).
// BM=64 -> grid 2x more blocks -> 2 blocks/CU so barrier stalls overlap.
// ---------------------------------------------------------------------------
template <int BM, int BN>
__global__ __launch_bounds__(256) void k_gemm_bf16(
    const unsigned short* __restrict__ A, const unsigned short* __restrict__ W,
    const float* __restrict__ bias, unsigned short* __restrict__ C,
    const int K, const int N, const int relu)
{
    constexpr int WM = BM / 2, WN = BN / 2;
    constexpr int MM = WM / 16, NN = WN / 16;
    constexpr int NA = (BM * 8) / 256;
    constexpr int NB = (BN * 8) / 256;
    __shared__ unsigned short As[BM][72];
    __shared__ unsigned short Bs[BN][72];
    const int tid = threadIdx.x;
    const int wave = tid >> 6, lane = tid & 63;
    const int wm = wave >> 1, wn = wave & 1;
    const size_t m0 = (size_t)blockIdx.x * BM;
    const size_t n0 = (size_t)blockIdx.y * BN;

    f32x4 acc[MM][NN];
#pragma unroll
    for (int i = 0; i < MM; ++i)
#pragma unroll
        for (int j = 0; j < NN; ++j) acc[i][j] = (f32x4){0.f, 0.f, 0.f, 0.f};

    uint4 pa[NA], pb[NB];
    auto loadA = [&](int k0) {
#pragma unroll
        for (int j = 0; j < NA; ++j) {
            const int i = tid + j * 256;
            const int row = i >> 3, c8 = (i & 7) * 8;
            pa[j] = *(const uint4*)(A + (m0 + row) * (size_t)K + k0 + c8);
        }
    };
    auto loadB = [&](int k0) {
#pragma unroll
        for (int j = 0; j < NB; ++j) {
            const int i = tid + j * 256;
            const int row = i >> 3, c8 = (i & 7) * 8;
            pb[j] = *(const uint4*)(W + (n0 + row) * (size_t)K + k0 + c8);
        }
    };

    loadA(0);
    loadB(0);
    for (int k0 = 0; k0 < K; k0 += 64) {
        __syncthreads();
#pragma unroll
        for (int j = 0; j < NA; ++j) {
            const int i = tid + j * 256;
            const int row = i >> 3, c8 = (i & 7) * 8;
            *(uint4*)&As[row][c8] = pa[j];
        }
#pragma unroll
        for (int j = 0; j < NB; ++j) {
            const int i = tid + j * 256;
            const int row = i >> 3, c8 = (i & 7) * 8;
            *(uint4*)&Bs[row][c8] = pb[j];
        }
        __syncthreads();
        if (k0 + 64 < K) { loadA(k0 + 64); loadB(k0 + 64); }
#pragma unroll
        for (int kk = 0; kk < 2; ++kk) {
            const int krow = kk * 32 + (lane >> 4) * 8;
            bf16x8 af[MM], bfr[NN];
#pragma unroll
            for (int mm = 0; mm < MM; ++mm)
                af[mm] = *(const bf16x8*)&As[wm * WM + mm * 16 + (lane & 15)][krow];
#pragma unroll
            for (int nn = 0; nn < NN; ++nn)
                bfr[nn] = *(const bf16x8*)&Bs[wn * WN + nn * 16 + (lane & 15)][krow];
#pragma unroll
            for (int mm = 0; mm < MM; ++mm)
#pragma unroll
                for (int nn = 0; nn < NN; ++nn)
                    acc[mm][nn] = __builtin_amdgcn_mfma_f32_16x16x32_bf16(
                        af[mm], bfr[nn], acc[mm][nn], 0, 0, 0);
        }
    }

#pragma unroll
    for (int nn = 0; nn < NN; ++nn) {
        const int col = (int)n0 + wn * WN + nn * 16 + (lane & 15);
        const float bv = bias[col];
#pragma unroll
        for (int mm = 0; mm < MM; ++mm) {
#pragma unroll
            for (int r = 0; r < 4; ++r) {
                const size_t row = m0 + wm * WM + mm * 16 + (lane >> 4) * 4 + r;
                float v = acc[mm][nn][r] + bv;
                if (relu) v = fmaxf(v, 0.f);
                C[row * N + col] = (unsigned short)f2bf(v);
            }
        }
    }
}

// ---------------------------------------------------------------------------
// Fused gemm2+gemm3+final.  One block = 64 batch rows.
// Stage 1: h2[64x256] = relu(h1[64x512] @ w2^T + b2) -> LDS bf16 (padded).
// Stage 2: h3[64x128] = relu(h2 @ w3^T + b3), in registers.
// Stage 3: deep = h3 . d4w + d4b; out = sigmoid(ww*sigmoid(wide)+dw*deep+bs).
// Eliminates h2/h3 global round-trips and two kernel launches.
// ---------------------------------------------------------------------------
__global__ __launch_bounds__(256) void k_gemm23f(
    const unsigned short* __restrict__ h1, const unsigned short* __restrict__ w2,
    const float* __restrict__ b2, const unsigned short* __restrict__ w3,
    const float* __restrict__ b3, const float* __restrict__ d4w,
    const float* __restrict__ d4b, const float* __restrict__ wl,
    const float* __restrict__ wwt, const float* __restrict__ dwt,
    const float* __restrict__ bs, float* __restrict__ out)
{
    __shared__ unsigned short As[64][72];
    __shared__ unsigned short Bs[256][72];
    __shared__ unsigned short h2l[64][264];   // bf16, 8-elem pad
    __shared__ float dp[64][2];
    const int tid = threadIdx.x;
    const int wave = tid >> 6, lane = tid & 63;
    const int wm = wave >> 1, wn = wave & 1;
    const size_t m0 = (size_t)blockIdx.x * 64;

    // ---- stage 1: K=512, BK=64, 8 iterations; N=256 (all cols) ----
    f32x4 acc[2][8];
#pragma unroll
    for (int i = 0; i < 2; ++i)
#pragma unroll
        for (int j = 0; j < 8; ++j) acc[i][j] = (f32x4){0.f, 0.f, 0.f, 0.f};

    uint4 pa[2], pb[8];
    auto loadA = [&](int k0) {
#pragma unroll
        for (int j = 0; j < 2; ++j) {
            const int i = tid + j * 256;
            const int row = i >> 3, c8 = (i & 7) * 8;
            pa[j] = *(const uint4*)(h1 + (m0 + row) * 512 + k0 + c8);
        }
    };
    auto loadB = [&](int k0) {
#pragma unroll
        for (int j = 0; j < 8; ++j) {
            const int i = tid + j * 256;
            const int row = i >> 3, c8 = (i & 7) * 8;
            pb[j] = *(const uint4*)(w2 + (size_t)row * 512 + k0 + c8);
        }
    };

    loadA(0);
    loadB(0);
    for (int k0 = 0; k0 < 512; k0 += 64) {
        __syncthreads();
#pragma unroll
        for (int j = 0; j < 2; ++j) {
            const int i = tid + j * 256;
            const int row = i >> 3, c8 = (i & 7) * 8;
            *(uint4*)&As[row][c8] = pa[j];
        }
#pragma unroll
        for (int j = 0; j < 8; ++j) {
            const int i = tid + j * 256;
            const int row = i >> 3, c8 = (i & 7) * 8;
            *(uint4*)&Bs[row][c8] = pb[j];
        }
        __syncthreads();
        if (k0 + 64 < 512) { loadA(k0 + 64); loadB(k0 + 64); }
#pragma unroll
        for (int kk = 0; kk < 2; ++kk) {
            const int krow = kk * 32 + (lane >> 4) * 8;
            bf16x8 af[2], bfr[8];
#pragma unroll
            for (int mm = 0; mm < 2; ++mm)
                af[mm] = *(const bf16x8*)&As[wm * 32 + mm * 16 + (lane & 15)][krow];
#pragma unroll
            for (int nn = 0; nn < 8; ++nn)
                bfr[nn] = *(const bf16x8*)&Bs[wn * 128 + nn * 16 + (lane & 15)][krow];
#pragma unroll
            for (int mm = 0; mm < 2; ++mm)
#pragma unroll
                for (int nn = 0; nn < 8; ++nn)
                    acc[mm][nn] = __builtin_amdgcn_mfma_f32_16x16x32_bf16(
                        af[mm], bfr[nn], acc[mm][nn], 0, 0, 0);
        }
    }
    // epilogue -> h2 in LDS (bf16 + relu + bias)
#pragma unroll
    for (int nn = 0; nn < 8; ++nn) {
        const int col = wn * 128 + nn * 16 + (lane & 15);
        const float bv = b2[col];
#pragma unroll
        for (int mm = 0; mm < 2; ++mm) {
#pragma unroll
            for (int r = 0; r < 4; ++r) {
                const int row = wm * 32 + mm * 16 + (lane >> 4) * 4 + r;
                h2l[row][col] = (unsigned short)f2bf(fmaxf(acc[mm][nn][r] + bv, 0.f));
            }
        }
    }
    __syncthreads();

    // ---- stage 2: h3 = relu(h2l @ w3^T + b3), K=256, N=128, 4 iterations ----
    f32x4 acc2[2][4];
#pragma unroll
    for (int i = 0; i < 2; ++i)
#pragma unroll
        for (int j = 0; j < 4; ++j) acc2[i][j] = (f32x4){0.f, 0.f, 0.f, 0.f};

    for (int k0 = 0; k0 < 256; k0 += 64) {
#pragma unroll
        for (int j = 0; j < 4; ++j) {
            const int i = tid + j * 256;
            const int row = i >> 3, c8 = (i & 7) * 8;
            *(uint4*)&Bs[row][c8] = *(const uint4*)(w3 + (size_t)row * 256 + k0 + c8);
        }
        __syncthreads();
#pragma unroll
        for (int kk = 0; kk < 2; ++kk) {
            const int krow = kk * 32 + (lane >> 4) * 8;
            bf16x8 af[2], bfr[4];
#pragma unroll
            for (int mm = 0; mm < 2; ++mm)
                af[mm] = *(const bf16x8*)&h2l[wm * 32 + mm * 16 + (lane & 15)][k0 + krow];
#pragma unroll
            for (int nn = 0; nn < 4; ++nn)
                bfr[nn] = *(const bf16x8*)&Bs[wn * 64 + nn * 16 + (lane & 15)][krow];
#pragma unroll
            for (int mm = 0; mm < 2; ++mm)
#pragma unroll
                for (int nn = 0; nn < 4; ++nn)
                    acc2[mm][nn] = __builtin_amdgcn_mfma_f32_16x16x32_bf16(
                        af[mm], bfr[nn], acc2[mm][nn], 0, 0, 0);
        }
        __syncthreads();
    }

    // ---- stage 3: per-row dot with d4w, then final sigmoid ----
    float rowpart[2][4];
#pragma unroll
    for (int mm = 0; mm < 2; ++mm)
#pragma unroll
        for (int r = 0; r < 4; ++r) rowpart[mm][r] = 0.f;
#pragma unroll
    for (int nn = 0; nn < 4; ++nn) {
        const int col = wn * 64 + nn * 16 + (lane & 15);
        const float bv = b3[col];
        const float w4 = d4w[col];
#pragma unroll
        for (int mm = 0; mm < 2; ++mm)
#pragma unroll
            for (int r = 0; r < 4; ++r)
                rowpart[mm][r] += fmaxf(acc2[mm][nn][r] + bv, 0.f) * w4;
    }
#pragma unroll
    for (int mm = 0; mm < 2; ++mm)
#pragma unroll
        for (int r = 0; r < 4; ++r) {
            float v = rowpart[mm][r];
            v += __shfl_xor(v, 1, 64);
            v += __shfl_xor(v, 2, 64);
            v += __shfl_xor(v, 4, 64);
            v += __shfl_xor(v, 8, 64);
            if ((lane & 15) == 0)
                dp[wm * 32 + mm * 16 + (lane >> 4) * 4 + r][wn] = v;
        }
    __syncthreads();
    if (tid < 64) {
        const float deep = dp[tid][0] + dp[tid][1] + d4b[0];
        const size_t b = m0 + tid;
        const float wo = 1.f / (1.f + __expf(-wl[b]));
        const float z = wwt[0] * wo + dwt[0] * deep + bs[0];
        out[b] = 1.f / (1.f + __expf(-z));
    }
}

extern "C" void kernel_launch(void* const* d_in, const int* in_sizes, int n_in,
                              void* d_out, int out_size, void* d_ws, size_t ws_size,
                              hipStream_t stream)
{
    const float* mt    = (const float*)d_in[0];
    const float* tt    = (const float*)d_in[1];
    const float* cp    = (const float*)d_in[2];
    const float* X     = (const float*)d_in[3];
    const float* cand  = (const float*)d_in[4];
    const float* mdesc = (const float*)d_in[5];
    const int*   clen  = (const int*)d_in[6];
    const float* WK    = (const float*)d_in[7];
    const float* WQ    = (const float*)d_in[8];
    const float* ww    = (const float*)d_in[9];
    const float* wb    = (const float*)d_in[10];
    const float* d1w   = (const float*)d_in[11];
    const float* d1b   = (const float*)d_in[12];
    const float* d2w   = (const float*)d_in[13];
    const float* d2b   = (const float*)d_in[14];
    const float* d3w   = (const float*)d_in[15];
    const float* d3b   = (const float*)d_in[16];
    const float* d4w   = (const float*)d_in[17];
    const float* d4b   = (const float*)d_in[18];
    const float* wwt   = (const float*)d_in[19];
    const float* dwt   = (const float*)d_in[20];
    const float* bs    = (const float*)d_in[21];
    float* out = (float*)d_out;

    // workspace layout (bytes)
    char* w = (char*)d_ws;
    unsigned short* din = (unsigned short*)w;            w += (size_t)Bsz * 1536 * 2;
    float* qt           = (float*)w;                     w += (size_t)Bsz * 512 * 4;
    unsigned short* h1  = (unsigned short*)w;            w += (size_t)Bsz * 512 * 2;
    float* wl           = (float*)w;                     w += (size_t)Bsz * 4;
    unsigned short* w1b = (unsigned short*)w;            w += (size_t)512 * 1536 * 2;
    unsigned short* w2b = (unsigned short*)w;            w += (size_t)256 * 512 * 2;
    unsigned short* w3b = (unsigned short*)w;            w += (size_t)128 * 256 * 2;

    hipLaunchKernelGGL(k_prep, dim3(1952), dim3(256), 0, stream,
                       cand, WQ, WK, qt, d1w, w1b, d2w, w2b, d3w, w3b);
    hipLaunchKernelGGL(k_attn_wide, dim3(Bsz), dim3(256), 0, stream,
                       X, qt, clen, mdesc, cand, mt, tt, cp, ww, wb, din, wl);
    hipLaunchKernelGGL((k_gemm_bf16<64, 128>), dim3(128, 4), dim3(256), 0, stream,
                       din, w1b, d1b, h1, 1536, 512, 1);
    hipLaunchKernelGGL(k_gemm23f, dim3(128), dim3(256), 0, stream,
                       h1, w2b, d2b, w3b, d3b, d4w, d4b, wl, wwt, dwt, bs, out);
}

// Round 17
// 396.372 us; speedup vs baseline: 1.5924x; 1.0519x over previous
//
#include <hip/hip_runtime.h>

#define Bsz 8192
#define Lctx 64
#define Ddim 512
#define DK 64
#define Ttag 128
#define RQT 2   // batch rows per wave in qtilde part of k_prep

using f32x4 = __attribute__((ext_vector_type(4))) float;
using bf16x8 = __attribute__((ext_vector_type(8))) short;

__device__ __forceinline__ float wave_sum(float v) {
#pragma unroll
    for (int m = 32; m > 0; m >>= 1) v += __shfl_xor(v, m, 64);
    return v;
}

__device__ __forceinline__ float wave_max(float v) {
#pragma unroll
    for (int m = 32; m > 0; m >>= 1) v = fmaxf(v, __shfl_xor(v, m, 64));
    return v;
}

__device__ __forceinline__ float dot4(float4 a, float4 b) {
    return a.x * b.x + a.y * b.y + a.z * b.z + a.w * b.w;
}

__device__ __forceinline__ unsigned f2bf(float f) {  // RNE, low 16 valid
    unsigned int u = __float_as_uint(f);
    u = u + 0x7fffu + ((u >> 16) & 1u);
    return u >> 16;
}
__device__ __forceinline__ unsigned pack2(float a, float b) {
    return f2bf(a) | (f2bf(b) << 16);
}
__device__ __forceinline__ float bf2f(unsigned short u) { return __uint_as_float((unsigned)u << 16); }

// ---------------------------------------------------------------------------
// Prep: blocks [0,1024) compute q̃ (RQT=2 rows/wave); blocks [1024,1952)
// convert the three MLP weights fp32->bf16 (f2bf blocks fill idle CUs).
// ---------------------------------------------------------------------------
__global__ __launch_bounds__(256) void k_prep(
    const float* __restrict__ C, const float* __restrict__ WQ,
    const float* __restrict__ WK, float* __restrict__ qt,
    const float* __restrict__ s1, unsigned short* __restrict__ d1,
    const float* __restrict__ s2, unsigned short* __restrict__ d2,
    const float* __restrict__ s3, unsigned short* __restrict__ d3)
{
    if (blockIdx.x >= 1024) {
        int i = (blockIdx.x - 1024) * 256 + threadIdx.x;   // < 237568 by grid
        const float* s;
        unsigned short* d;
        if (i < 196608)      { s = s1; d = d1; }
        else if (i < 229376) { i -= 196608; s = s2; d = d2; }
        else                 { i -= 229376; s = s3; d = d3; }
        const float4 v = ((const float4*)s)[i];
        uint2 w;
        w.x = pack2(v.x, v.y);
        w.y = pack2(v.z, v.w);
        *(uint2*)&d[(size_t)i * 4] = w;
        return;
    }

    const int lane = threadIdx.x & 63;
    const int gw = blockIdx.x * 4 + (threadIdx.x >> 6);
    const int b0 = gw * RQT;

    float4 c0[RQT], c1[RQT];
#pragma unroll
    for (int r = 0; r < RQT; ++r) {
        const float4* row = (const float4*)(C + (size_t)(b0 + r) * Ddim);
        c0[r] = row[lane];
        c1[r] = row[64 + lane];
    }
    float tv[RQT];
#pragma unroll
    for (int r = 0; r < RQT; ++r) tv[r] = 0.f;
    for (int k = 0; k < DK; ++k) {
        const float4* wrow = (const float4*)(WQ + (size_t)k * Ddim);
        const float4 w0 = wrow[lane];
        const float4 w1 = wrow[64 + lane];
#pragma unroll
        for (int r = 0; r < RQT; ++r) {
            float p = dot4(c0[r], w0) + dot4(c1[r], w1);
            p = wave_sum(p);
            if (lane == k) tv[r] = p;
        }
    }
    float4 a0[RQT], a1[RQT];
#pragma unroll
    for (int r = 0; r < RQT; ++r) {
        a0[r] = make_float4(0.f, 0.f, 0.f, 0.f);
        a1[r] = make_float4(0.f, 0.f, 0.f, 0.f);
    }
    for (int k = 0; k < DK; ++k) {
        const float4* wrow = (const float4*)(WK + (size_t)k * Ddim);
        const float4 w0 = wrow[lane];
        const float4 w1 = wrow[64 + lane];
#pragma unroll
        for (int r = 0; r < RQT; ++r) {
            const float tk = __shfl(tv[r], k, 64);
            a0[r].x += tk * w0.x; a0[r].y += tk * w0.y;
            a0[r].z += tk * w0.z; a0[r].w += tk * w0.w;
            a1[r].x += tk * w1.x; a1[r].y += tk * w1.y;
            a1[r].z += tk * w1.z; a1[r].w += tk * w1.w;
        }
    }
#pragma unroll
    for (int r = 0; r < RQT; ++r) {
        float4* orow = (float4*)(qt + (size_t)(b0 + r) * Ddim);
        orow[lane] = a0[r];
        orow[64 + lane] = a1[r];
    }
}

// ---------------------------------------------------------------------------
// Fused ragged attention + wide — R13's lean flash-partial kernel, verbatim
// (measured 224 us = 5.1 TB/s = 81% HBM, the machine's demonstrated ceiling).
// ---------------------------------------------------------------------------
__global__ __launch_bounds__(256, 8) void k_attn_wide(
    const float* __restrict__ X, const float* __restrict__ qt,
    const int* __restrict__ clen, const float* __restrict__ mdesc,
    const float* __restrict__ cand,
    const float* __restrict__ mt, const float* __restrict__ tt,
    const float* __restrict__ cp, const float* __restrict__ ww,
    const float* __restrict__ wb,
    unsigned short* __restrict__ din, float* __restrict__ wl)
{
    __shared__ float sl[Lctx];
    __shared__ float part[4][Ddim];
    __shared__ float Mw[4];
    __shared__ float red[4];
    __shared__ float MD[2];

    const int b = blockIdx.x;
    const int tid = threadIdx.x;
    const int wave = tid >> 6, lane = tid & 63;
    const int len = clen[b];
    const int nrw = (len > wave) ? ((len - wave + 3) >> 2) : 0;

    const float4* xb = (const float4*)(X + (size_t)b * Lctx * Ddim);

    float4 y0 = make_float4(0.f, 0.f, 0.f, 0.f);
    float4 y1 = make_float4(0.f, 0.f, 0.f, 0.f);
    float mw = -1e30f;

    if (nrw > 0) {
        const float4* qrow = (const float4*)(qt + (size_t)b * Ddim);
        const float4 q0 = qrow[lane];
        const float4 q1 = qrow[64 + lane];
        for (int k = 0; k < nrw; k += 2) {
            const int l0 = wave + k * 4;
            const int l1 = wave + min(k + 1, nrw - 1) * 4;
            const float4 a0 = xb[l0 * 128 + lane];
            const float4 a1 = xb[l0 * 128 + 64 + lane];
            const float4 c0 = xb[l1 * 128 + lane];
            const float4 c1 = xb[l1 * 128 + 64 + lane];
            float s0 = dot4(a0, q0) + dot4(a1, q1);
            float s1 = dot4(c0, q0) + dot4(c1, q1);
            s0 = wave_sum(s0);
            s1 = wave_sum(s1);
            const bool has1 = (k + 1 < nrw);
            if (lane == 0) {
                sl[l0] = s0;
                if (has1) sl[l1] = s1;
            }
            const float pm = has1 ? fmaxf(s0, s1) : s0;
            const float mn = fmaxf(mw, pm);
            const float scale = __expf(mw - mn);
            const float e0 = __expf(s0 - mn);
            const float e1 = has1 ? __expf(s1 - mn) : 0.f;
            y0.x = y0.x * scale + e0 * a0.x + e1 * c0.x;
            y0.y = y0.y * scale + e0 * a0.y + e1 * c0.y;
            y0.z = y0.z * scale + e0 * a0.z + e1 * c0.z;
            y0.w = y0.w * scale + e0 * a0.w + e1 * c0.w;
            y1.x = y1.x * scale + e0 * a1.x + e1 * c1.x;
            y1.y = y1.y * scale + e0 * a1.y + e1 * c1.y;
            y1.z = y1.z * scale + e0 * a1.z + e1 * c1.z;
            y1.w = y1.w * scale + e0 * a1.w + e1 * c1.w;
            mw = mn;
        }
    }
    *(float4*)&part[wave][lane * 4] = y0;
    *(float4*)&part[wave][256 + lane * 4] = y1;
    if (lane == 0) Mw[wave] = mw;

    float wacc = 0.f;
    if (tid < 64) {
        float4 v;
        if (tid < 32) v = ((const float4*)(mt + (size_t)b * Ttag))[tid];
        else          v = ((const float4*)(tt + (size_t)b * Ttag))[tid - 32];
        wacc += dot4(v, ((const float4*)ww)[tid]);
    }
    {
        const float4* cp4 = (const float4*)(cp + (size_t)b * (Ttag * Ttag));
        const float4* ww4 = (const float4*)(ww + 2 * Ttag);
#pragma unroll 2
        for (int i = tid; i < (Ttag * Ttag) / 4; i += 256)
            wacc += dot4(cp4[i], ww4[i]);
    }
    wacc = wave_sum(wacc);
    if (lane == 0) red[wave] = wacc;

    const float4 mv = (tid < 128)
        ? ((const float4*)(mdesc + (size_t)b * Ddim))[tid]
        : ((const float4*)(cand + (size_t)b * Ddim))[tid - 128];

    __syncthreads();

    if (wave == 0) {
        const float s = (lane < len) ? sl[lane] : -1e30f;
        const float m = wave_max(s);
        const float e = (lane < len) ? __expf(s - m) : 0.f;
        const float d = wave_sum(e);
        if (lane == 0) {
            MD[0] = m;
            MD[1] = 1.f / fmaxf(d, 1e-30f);
        }
    }
    __syncthreads();

    const float Mg = MD[0], rD = MD[1];
    const float f0 = __expf(Mw[0] - Mg) * rD;
    const float f1 = __expf(Mw[1] - Mg) * rD;
    const float f2 = __expf(Mw[2] - Mg) * rD;
    const float f3 = __expf(Mw[3] - Mg) * rD;

    unsigned short* dr = din + (size_t)b * 1536;
    {
        const int d0 = tid * 2;
        const float2 p0 = *(const float2*)&part[0][d0];
        const float2 p1 = *(const float2*)&part[1][d0];
        const float2 p2 = *(const float2*)&part[2][d0];
        const float2 p3 = *(const float2*)&part[3][d0];
        const float vx = p0.x * f0 + p1.x * f1 + p2.x * f2 + p3.x * f3;
        const float vy = p0.y * f0 + p1.y * f1 + p2.y * f2 + p3.y * f3;
        *(unsigned*)&dr[512 + d0] = pack2(vx, vy);
    }
    {
        uint2 w;
        w.x = pack2(mv.x, mv.y);
        w.y = pack2(mv.z, mv.w);
        const int off = (tid < 128) ? tid * 4 : 1024 + (tid - 128) * 4;
        *(uint2*)&dr[off] = w;
    }
    if (tid == 0) wl[b] = red[0] + red[1] + red[2] + red[3] + wb[0];
}

// ---------------------------------------------------------------------------
// bf16 MFMA GEMM templated on BM/BN.  4 waves in 2x2, per-wave (BM/2)x(BN/2).
// gemm1 uses BM=128 (the R13-proven config); gemm2/3 use BM=64 to fill CUs.
// ---------------------------------------------------------------------------
template <int BM, int BN>
__global__ __launch_bounds__(256) void k_gemm_bf16(
    const unsigned short* __restrict__ A, const unsigned short* __restrict__ W,
    const float* __restrict__ bias, unsigned short* __restrict__ C,
    const int K, const int N, const int relu)
{
    constexpr int WM = BM / 2, WN = BN / 2;
    constexpr int MM = WM / 16, NN = WN / 16;
    constexpr int NA = (BM * 8) / 256;
    constexpr int NB = (BN * 8) / 256;
    __shared__ unsigned short As[BM][72];
    __shared__ unsigned short Bs[BN][72];
    const int tid = threadIdx.x;
    const int wave = tid >> 6, lane = tid & 63;
    const int wm = wave >> 1, wn = wave & 1;
    const size_t m0 = (size_t)blockIdx.x * BM;
    const size_t n0 = (size_t)blockIdx.y * BN;

    f32x4 acc[MM][NN];
#pragma unroll
    for (int i = 0; i < MM; ++i)
#pragma unroll
        for (int j = 0; j < NN; ++j) acc[i][j] = (f32x4){0.f, 0.f, 0.f, 0.f};

    uint4 pa[NA], pb[NB];
    auto loadA = [&](int k0) {
#pragma unroll
        for (int j = 0; j < NA; ++j) {
            const int i = tid + j * 256;
            const int row = i >> 3, c8 = (i & 7) * 8;
            pa[j] = *(const uint4*)(A + (m0 + row) * (size_t)K + k0 + c8);
        }
    };
    auto loadB = [&](int k0) {
#pragma unroll
        for (int j = 0; j < NB; ++j) {
            const int i = tid + j * 256;
            const int row = i >> 3, c8 = (i & 7) * 8;
            pb[j] = *(const uint4*)(W + (n0 + row) * (size_t)K + k0 + c8);
        }
    };

    loadA(0);
    loadB(0);
    for (int k0 = 0; k0 < K; k0 += 64) {
        __syncthreads();
#pragma unroll
        for (int j = 0; j < NA; ++j) {
            const int i = tid + j * 256;
            const int row = i >> 3, c8 = (i & 7) * 8;
            *(uint4*)&As[row][c8] = pa[j];
        }
#pragma unroll
        for (int j = 0; j < NB; ++j) {
            const int i = tid + j * 256;
            const int row = i >> 3, c8 = (i & 7) * 8;
            *(uint4*)&Bs[row][c8] = pb[j];
        }
        __syncthreads();
        if (k0 + 64 < K) { loadA(k0 + 64); loadB(k0 + 64); }
#pragma unroll
        for (int kk = 0; kk < 2; ++kk) {
            const int krow = kk * 32 + (lane >> 4) * 8;
            bf16x8 af[MM], bfr[NN];
#pragma unroll
            for (int mm = 0; mm < MM; ++mm)
                af[mm] = *(const bf16x8*)&As[wm * WM + mm * 16 + (lane & 15)][krow];
#pragma unroll
            for (int nn = 0; nn < NN; ++nn)
                bfr[nn] = *(const bf16x8*)&Bs[wn * WN + nn * 16 + (lane & 15)][krow];
#pragma unroll
            for (int mm = 0; mm < MM; ++mm)
#pragma unroll
                for (int nn = 0; nn < NN; ++nn)
                    acc[mm][nn] = __builtin_amdgcn_mfma_f32_16x16x32_bf16(
                        af[mm], bfr[nn], acc[mm][nn], 0, 0, 0);
        }
    }

#pragma unroll
    for (int nn = 0; nn < NN; ++nn) {
        const int col = (int)n0 + wn * WN + nn * 16 + (lane & 15);
        const float bv = bias[col];
#pragma unroll
        for (int mm = 0; mm < MM; ++mm) {
#pragma unroll
            for (int r = 0; r < 4; ++r) {
                const size_t row = m0 + wm * WM + mm * 16 + (lane >> 4) * 4 + r;
                float v = acc[mm][nn][r] + bv;
                if (relu) v = fmaxf(v, 0.f);
                C[row * N + col] = (unsigned short)f2bf(v);
            }
        }
    }
}

// ---------------------------------------------------------------------------
// Final: deep_out = h3 . d4w + d4b; out = sigmoid(ww*sigmoid(wide)+dw*deep+bias)
// ---------------------------------------------------------------------------
__global__ __launch_bounds__(256) void k_final(
    const unsigned short* __restrict__ h3, const float* __restrict__ d4w,
    const float* __restrict__ d4b, const float* __restrict__ wl,
    const float* __restrict__ wwt, const float* __restrict__ dwt,
    const float* __restrict__ bs, float* __restrict__ out)
{
    const int lane = threadIdx.x & 63;
    const int b = blockIdx.x * 4 + (threadIdx.x >> 6);
    const unsigned short* hr = h3 + (size_t)b * 128;
    float v = bf2f(hr[lane]) * d4w[lane] + bf2f(hr[64 + lane]) * d4w[64 + lane];
    v = wave_sum(v);
    if (lane == 0) {
        const float deep = v + d4b[0];
        const float wo = 1.f / (1.f + __expf(-wl[b]));
        const float z = wwt[0] * wo + dwt[0] * deep + bs[0];
        out[b] = 1.f / (1.f + __expf(-z));
    }
}

extern "C" void kernel_launch(void* const* d_in, const int* in_sizes, int n_in,
                              void* d_out, int out_size, void* d_ws, size_t ws_size,
                              hipStream_t stream)
{
    const float* mt    = (const float*)d_in[0];
    const float* tt    = (const float*)d_in[1];
    const float* cp    = (const float*)d_in[2];
    const float* X     = (const float*)d_in[3];
    const float* cand  = (const float*)d_in[4];
    const float* mdesc = (const float*)d_in[5];
    const int*   clen  = (const int*)d_in[6];
    const float* WK    = (const float*)d_in[7];
    const float* WQ    = (const float*)d_in[8];
    const float* ww    = (const float*)d_in[9];
    const float* wb    = (const float*)d_in[10];
    const float* d1w   = (const float*)d_in[11];
    const float* d1b   = (const float*)d_in[12];
    const float* d2w   = (const float*)d_in[13];
    const float* d2b   = (const float*)d_in[14];
    const float* d3w   = (const float*)d_in[15];
    const float* d3b   = (const float*)d_in[16];
    const float* d4w   = (const float*)d_in[17];
    const float* d4b   = (const float*)d_in[18];
    const float* wwt   = (const float*)d_in[19];
    const float* dwt   = (const float*)d_in[20];
    const float* bs    = (const float*)d_in[21];
    float* out = (float*)d_out;

    // workspace layout (bytes)
    char* w = (char*)d_ws;
    unsigned short* din = (unsigned short*)w;            w += (size_t)Bsz * 1536 * 2;
    float* qt           = (float*)w;                     w += (size_t)Bsz * 512 * 4;
    unsigned short* h1  = (unsigned short*)w;            w += (size_t)Bsz * 512 * 2;
    unsigned short* h2  = (unsigned short*)w;            w += (size_t)Bsz * 256 * 2;
    unsigned short* h3  = (unsigned short*)w;            w += (size_t)Bsz * 128 * 2;
    float* wl           = (float*)w;                     w += (size_t)Bsz * 4;
    unsigned short* w1b = (unsigned short*)w;            w += (size_t)512 * 1536 * 2;
    unsigned short* w2b = (unsigned short*)w;            w += (size_t)256 * 512 * 2;
    unsigned short* w3b = (unsigned short*)w;            w += (size_t)128 * 256 * 2;

    hipLaunchKernelGGL(k_prep, dim3(1952), dim3(256), 0, stream,
                       cand, WQ, WK, qt, d1w, w1b, d2w, w2b, d3w, w3b);
    hipLaunchKernelGGL(k_attn_wide, dim3(Bsz), dim3(256), 0, stream,
                       X, qt, clen, mdesc, cand, mt, tt, cp, ww, wb, din, wl);
    hipLaunchKernelGGL((k_gemm_bf16<128, 128>), dim3(64, 4), dim3(256), 0, stream,
                       din, w1b, d1b, h1, 1536, 512, 1);
    hipLaunchKernelGGL((k_gemm_bf16<64, 128>), dim3(128, 2), dim3(256), 0, stream,
                       h1, w2b, d2b, h2, 512, 256, 1);
    hipLaunchKernelGGL((k_gemm_bf16<64, 128>), dim3(128, 1), dim3(256), 0, stream,
                       h2, w3b, d3b, h3, 256, 128, 1);
    hipLaunchKernelGGL(k_final, dim3(Bsz / 4), dim3(256), 0, stream,
                       h3, d4w, d4b, wl, wwt, dwt, bs, out);
}